// Round 7
// baseline (202.982 us; speedup 1.0000x reference)
//
#include <hip/hip_runtime.h>
#include <math.h>

// KShape dists via bf16 MFMA. B=256, K=16, SZ=512, D=8.
// corr[b,i,k] = sum_{t,d} xpad[b][(i+t)*8+d] * c[k][t*8+d],  i in [0,1022] (lag s=i-511)
// dists[b,k] = max_i corr / (||x_b|| * k); k=0 -> 0. labels = first argmax.
// out: [0..255]=labels(float), [256..4351]=dists.
//
// R7: 256 blocks x 512 threads, __launch_bounds__(512,4) -> 2 blocks/CU
// (16 waves/CU, R6-proven TLP). 8 row-tiles/wave via 32-slot LDS A-ring
// (1 ds_read_b128 feeds 8 MFMAs). Trapezoid skip as wave-uniform kc windows
// with klo down-aligned to 32 -> unroll-32 body keeps compile-time ring
// indices, zero interior branches (R5 spill trap avoided). Windows
// {64,96,128,128,128,96,64,32} = 736 B-loads/block (-36% B-L2 vs R6).
// B prefetch FIFO depth 8.

#define NB 256
#define NK 16
#define NS 512
#define ND 8
#define BAND 1560   // max refill row = 128*4 + 18 + 4*127 + 128 = 1166 < 1560

typedef __bf16 bf16x8 __attribute__((ext_vector_type(8)));
typedef float floatx4 __attribute__((ext_vector_type(4)));

// ---- pack centers into B-fragment order ----
// Bpk[kc*64 + L][0..8) = bf16( c[n = L&15][ (kc*4 + (L>>4))*8 + j ] )  j=0..7
__global__ void pack_kernel(const float* __restrict__ c, __bf16* __restrict__ bpk)
{
    int kc = blockIdx.x;      // 0..127 chunk of 32 contraction elems
    int L  = threadIdx.x;     // 0..63
    int n = L & 15, quad = L >> 4;
    const float4* src = (const float4*)(c + ((size_t)n * NS + (size_t)(kc * 4 + quad)) * ND);
    float4 a = src[0], b = src[1];
    bf16x8 v;
    v[0] = (__bf16)a.x; v[1] = (__bf16)a.y; v[2] = (__bf16)a.z; v[3] = (__bf16)a.w;
    v[4] = (__bf16)b.x; v[5] = (__bf16)b.y; v[6] = (__bf16)b.z; v[7] = (__bf16)b.w;
    *(bf16x8*)(bpk + ((size_t)kc * 64 + L) * 8) = v;
}

// ---- main: one block = one b; 8 waves x 8 row-tiles = 1024 lag rows ----
__global__ __launch_bounds__(512, 4) void dists_mfma(
    const float* __restrict__ x, const __bf16* __restrict__ bpk, float* __restrict__ out)
{
    __shared__ __align__(16) __bf16 xq[BAND * 8];   // 24.4 KB
    __shared__ float wred[8][16];
    __shared__ float redn[8];
    __shared__ float s_norm;
    __shared__ float dd[16];

    const int tid = threadIdx.x;
    const int b   = blockIdx.x;

    // stage padded x band (bf16) + accumulate sum of squares (f32, for norm)
    float ss = 0.f;
    for (int jj = tid; jj < BAND; jj += 512) {
        bf16x8 v;
        if (jj >= 511 && jj < 1023) {
            const float4* p = (const float4*)(x + ((size_t)b * NS + (size_t)(jj - 511)) * ND);
            float4 a = p[0], bb = p[1];
            ss += a.x * a.x + a.y * a.y + a.z * a.z + a.w * a.w;
            ss += bb.x * bb.x + bb.y * bb.y + bb.z * bb.z + bb.w * bb.w;
            v[0] = (__bf16)a.x;  v[1] = (__bf16)a.y;  v[2] = (__bf16)a.z;  v[3] = (__bf16)a.w;
            v[4] = (__bf16)bb.x; v[5] = (__bf16)bb.y; v[6] = (__bf16)bb.z; v[7] = (__bf16)bb.w;
        } else {
            #pragma unroll
            for (int e = 0; e < 8; ++e) v[e] = (__bf16)0.0f;
        }
        *(bf16x8*)(xq + (size_t)jj * 8) = v;
    }
    #pragma unroll
    for (int off = 32; off; off >>= 1) ss += __shfl_down(ss, off);
    if ((tid & 63) == 0) redn[tid >> 6] = ss;
    __syncthreads();
    if (tid == 0) {
        float t = 0.f;
        #pragma unroll
        for (int i = 0; i < 8; ++i) t += redn[i];
        s_norm = sqrtf(t);
    }

    const int L    = tid & 63;
    const int m    = L & 15;       // A row within tile / D col (center id)
    const int quad = L >> 4;
    const int wu   = __builtin_amdgcn_readfirstlane(tid >> 6);  // wave id 0..7

    // wave-uniform active kc window, klo down-aligned to 32:
    // tile (wu,r) nonzero iff 4kc in [492-128wu-16r-19, 1022-128wu-16r].
    // union over r: exact klo = max(0, ceil((380-128wu)/4)) = max(0, 95-32wu).
    const int a0  = 95 - 32 * wu;
    const int klo = (a0 > 0) ? (a0 & ~31) : 0;            // {64,32,0,0,...}
    const int kh_ = (1022 - 128 * wu) >> 2;
    const int khi = (kh_ > 127) ? 127 : kh_;              // {127*5,95,63,31}
    // window lengths: {64,96,128,128,128,96,64,32} -- all multiples of 32.

    // A-frag for (r, kc): 16B at gb + 8*(16r + 4kc); ring slot (kc + 4r) & 31
    const __bf16* gb = xq + 8 * (128 * wu + m + quad);
    const bf16x8* Bp = (const bf16x8*)bpk;

    // ring init: slot i holds row4 = klo + i  (klo % 32 == 0)
    bf16x8 Q[32];
    #pragma unroll
    for (int i = 0; i < 32; ++i) Q[i] = *(const bf16x8*)(gb + 32 * (klo + i));

    // B prefetch FIFO depth 8 (~300cy lookahead)
    bf16x8 Bv[8];
    #pragma unroll
    for (int i = 0; i < 8; ++i) Bv[i] = Bp[(size_t)(klo + i) * 64 + L];

    floatx4 acc[8] = {};

    for (int kc0 = klo; kc0 <= khi; kc0 += 32) {
        #pragma unroll
        for (int s = 0; s < 32; ++s) {
            const int kc = kc0 + s;
            bf16x8 bcur = Bv[s & 7];
            acc[0] = __builtin_amdgcn_mfma_f32_16x16x32_bf16(Q[(s + 0)  & 31], bcur, acc[0], 0, 0, 0);
            acc[1] = __builtin_amdgcn_mfma_f32_16x16x32_bf16(Q[(s + 4)  & 31], bcur, acc[1], 0, 0, 0);
            acc[2] = __builtin_amdgcn_mfma_f32_16x16x32_bf16(Q[(s + 8)  & 31], bcur, acc[2], 0, 0, 0);
            acc[3] = __builtin_amdgcn_mfma_f32_16x16x32_bf16(Q[(s + 12) & 31], bcur, acc[3], 0, 0, 0);
            acc[4] = __builtin_amdgcn_mfma_f32_16x16x32_bf16(Q[(s + 16) & 31], bcur, acc[4], 0, 0, 0);
            acc[5] = __builtin_amdgcn_mfma_f32_16x16x32_bf16(Q[(s + 20) & 31], bcur, acc[5], 0, 0, 0);
            acc[6] = __builtin_amdgcn_mfma_f32_16x16x32_bf16(Q[(s + 24) & 31], bcur, acc[6], 0, 0, 0);
            acc[7] = __builtin_amdgcn_mfma_f32_16x16x32_bf16(Q[(s + 28) & 31], bcur, acc[7], 0, 0, 0);
            // slot s dead after r=0 use this iter; refill with row4 = kc+32
            Q[s & 31] = *(const bf16x8*)(gb + 8 * (4 * kc + 128));
            Bv[s & 7] = Bp[(size_t)((kc + 8) & 127) * 64 + L];
        }
    }

    // D layout: col = lane&15 (center), row-in-tile = quad*4 + e.
    // global lag row = 128wu + 16r + 4quad + e; phantom row 1023 excluded.
    float vmax = -INFINITY;
    #pragma unroll
    for (int r = 0; r < 8; ++r) {
        #pragma unroll
        for (int e = 0; e < 4; ++e) {
            bool phantom = (wu == 7) & (r == 7) & (quad == 3) & (e == 3);
            vmax = fmaxf(vmax, phantom ? -INFINITY : acc[r][e]);
        }
    }
    vmax = fmaxf(vmax, __shfl_xor(vmax, 16));
    vmax = fmaxf(vmax, __shfl_xor(vmax, 32));
    if (quad == 0) wred[wu][m] = vmax;
    __syncthreads();

    if (tid < 16) {
        float mm = wred[0][tid];
        #pragma unroll
        for (int i = 1; i < 8; ++i) mm = fmaxf(mm, wred[i][tid]);
        float denom = s_norm * (float)tid;
        float d = (denom < 1e-9f) ? 0.f : mm / denom;
        dd[tid] = d;
        out[NB + b * NK + tid] = d;
    }
    __syncthreads();
    if (tid == 0) {
        float best = dd[0]; int lab = 0;
        #pragma unroll
        for (int k = 1; k < NK; ++k) if (dd[k] > best) { best = dd[k]; lab = k; }
        out[b] = (float)lab;
    }
}

extern "C" void kernel_launch(void* const* d_in, const int* in_sizes, int n_in,
                              void* d_out, int out_size, void* d_ws, size_t ws_size,
                              hipStream_t stream) {
    const float* x = (const float*)d_in[0];
    const float* c = (const float*)d_in[1];
    float* out = (float*)d_out;
    __bf16* bpk = (__bf16*)d_ws;    // 128 chunks * 1 KB = 128 KB

    pack_kernel<<<128, 64, 0, stream>>>(c, bpk);
    dists_mfma<<<NB, 512, 0, stream>>>(x, bpk, out);
}

// Round 8
// 73.551 us; speedup vs baseline: 2.7597x; 2.7597x over previous
//
#include <hip/hip_runtime.h>
#include <math.h>

// KShape dists via bf16 MFMA. B=256, K=16, SZ=512, D=8.
// corr[b,i,k] = sum_{t,d} xpad[b][(i+t)*8+d] * c[k][t*8+d],  i in [0,1022] (lag s=i-511)
// dists[b,k] = max_i corr / (||x_b|| * k); k=0 -> 0. labels = first argmax.
// out: [0..255]=labels(float), [256..4351]=dists.
//
// R8 = R6 (best, 74.4us) + B through LDS double-buffered 16-kc chunks.
// R6's spill-safe wave shape kept: 16 waves x 4 row-tiles, Q[16] LDS A-ring,
// wave-uniform trapezoid windows (klo,khi multiples of 16 -> chunk-aligned).
// Per chunk, all 1024 threads cooperatively stage the NEXT 16-kc chunk of
// packed B (16KB, one int4/thread) into the alternate buffer -- issued a
// full chunk (~1300cy) ahead, covering HBM/L2 latency; B-frag reads become
// LDS loads hidden by 4-wave/SIMD TLP. ~110 VGPR (128 cap at 4 waves/EU).

#define NB 256
#define NK 16
#define NS 512
#define ND 8
#define BAND 1120   // max refill row = 64*15 + 18 + 4*khi + 64 <= 1104 < 1120

typedef __bf16 bf16x8 __attribute__((ext_vector_type(8)));
typedef float floatx4 __attribute__((ext_vector_type(4)));

// ---- pack centers into B-fragment order ----
// Bpk[kc*64 + L][0..8) = bf16( c[n = L&15][ (kc*4 + (L>>4))*8 + j ] )  j=0..7
__global__ void pack_kernel(const float* __restrict__ c, __bf16* __restrict__ bpk)
{
    int kc = blockIdx.x;      // 0..127 chunk of 32 contraction elems
    int L  = threadIdx.x;     // 0..63
    int n = L & 15, quad = L >> 4;
    const float4* src = (const float4*)(c + ((size_t)n * NS + (size_t)(kc * 4 + quad)) * ND);
    float4 a = src[0], b = src[1];
    bf16x8 v;
    v[0] = (__bf16)a.x; v[1] = (__bf16)a.y; v[2] = (__bf16)a.z; v[3] = (__bf16)a.w;
    v[4] = (__bf16)b.x; v[5] = (__bf16)b.y; v[6] = (__bf16)b.z; v[7] = (__bf16)b.w;
    *(bf16x8*)(bpk + ((size_t)kc * 64 + L) * 8) = v;
}

// ---- main: one block = one b; 16 waves x 4 row-tiles = 1024 lag rows ----
__global__ __launch_bounds__(1024, 4) void dists_mfma(
    const float* __restrict__ x, const __bf16* __restrict__ bpk, float* __restrict__ out)
{
    __shared__ __align__(16) __bf16 xq[BAND * 8];       // 17.5 KB
    __shared__ __align__(16) __bf16 Bls[2][16 * 512];   // 32 KB double buffer
    __shared__ float wred[16][16];
    __shared__ float redn[16];
    __shared__ float s_norm;
    __shared__ float dd[16];

    const int tid = threadIdx.x;
    const int b   = blockIdx.x;

    // stage padded x band (bf16) + accumulate sum of squares (f32, for norm)
    float ss = 0.f;
    for (int jj = tid; jj < BAND; jj += 1024) {
        bf16x8 v;
        if (jj >= 511 && jj < 1023) {
            const float4* p = (const float4*)(x + ((size_t)b * NS + (size_t)(jj - 511)) * ND);
            float4 a = p[0], bb = p[1];
            ss += a.x * a.x + a.y * a.y + a.z * a.z + a.w * a.w;
            ss += bb.x * bb.x + bb.y * bb.y + bb.z * bb.z + bb.w * bb.w;
            v[0] = (__bf16)a.x;  v[1] = (__bf16)a.y;  v[2] = (__bf16)a.z;  v[3] = (__bf16)a.w;
            v[4] = (__bf16)bb.x; v[5] = (__bf16)bb.y; v[6] = (__bf16)bb.z; v[7] = (__bf16)bb.w;
        } else {
            #pragma unroll
            for (int e = 0; e < 8; ++e) v[e] = (__bf16)0.0f;
        }
        *(bf16x8*)(xq + (size_t)jj * 8) = v;
    }
    // stage B chunk 0 (16 kc = 16 KB = 1024 int4)
    const int4* bsrc = (const int4*)bpk;   // 128 kc * 64 lanes; int4 idx = kc*64 + lane
    ((int4*)Bls[0])[tid] = bsrc[tid];

    #pragma unroll
    for (int off = 32; off; off >>= 1) ss += __shfl_down(ss, off);
    if ((tid & 63) == 0) redn[tid >> 6] = ss;
    __syncthreads();
    if (tid == 0) {
        float t = 0.f;
        #pragma unroll
        for (int i = 0; i < 16; ++i) t += redn[i];
        s_norm = sqrtf(t);
    }

    const int L    = tid & 63;
    const int m    = L & 15;       // A row within tile / D col (center id)
    const int quad = L >> 4;
    const int wu   = __builtin_amdgcn_readfirstlane(tid >> 6);  // wave id 0..15

    // wave-uniform active kc window; klo,khi+1 multiples of 16 (chunk-aligned)
    const int a0  = 445 - 64 * wu;
    const int klo = (a0 > 0) ? ((a0 + 3) >> 2) : 0;    // 112,96,...,16,0,0,...
    const int kh_ = (1022 - 64 * wu) >> 2;
    const int khi = (kh_ > 127) ? 127 : kh_;           // 127 x8, 111, 95, ..., 15
    const int chlo = klo >> 4, chhi = khi >> 4;

    // A-frag for (r, kc): 16B at gb + 8*(16r + 4kc); ring slot (kc + 4r) & 15
    const __bf16* gb = xq + 8 * (64 * wu + m + quad);

    // ring init: slot i holds row4 = klo + i (klo % 16 == 0)
    bf16x8 Q[16];
    #pragma unroll
    for (int i = 0; i < 16; ++i) Q[i] = *(const bf16x8*)(gb + 8 * (4 * klo + 4 * i));

    floatx4 acc[4] = {};

    for (int ch = 0; ch < 8; ++ch) {
        // cooperatively stage NEXT chunk into the alternate buffer
        if (ch < 7) {
            int4 t = bsrc[(ch + 1) * 1024 + tid];
            ((int4*)Bls[(ch + 1) & 1])[tid] = t;
        }
        if (ch >= chlo && ch <= chhi) {
            const __bf16* bb = Bls[ch & 1] + L * 8;
            bf16x8 bcur = *(const bf16x8*)bb;
            #pragma unroll
            for (int s = 0; s < 16; ++s) {
                const int kc = ch * 16 + s;
                bf16x8 bnxt;
                if (s < 15) bnxt = *(const bf16x8*)(bb + (s + 1) * 512);
                acc[0] = __builtin_amdgcn_mfma_f32_16x16x32_bf16(Q[(s + 0)  & 15], bcur, acc[0], 0, 0, 0);
                acc[1] = __builtin_amdgcn_mfma_f32_16x16x32_bf16(Q[(s + 4)  & 15], bcur, acc[1], 0, 0, 0);
                acc[2] = __builtin_amdgcn_mfma_f32_16x16x32_bf16(Q[(s + 8)  & 15], bcur, acc[2], 0, 0, 0);
                acc[3] = __builtin_amdgcn_mfma_f32_16x16x32_bf16(Q[(s + 12) & 15], bcur, acc[3], 0, 0, 0);
                // slot s dead after r=0 use this iter; refill with row4 = kc+16
                Q[s & 15] = *(const bf16x8*)(gb + 8 * (4 * kc + 64));
                bcur = bnxt;
            }
        }
        __syncthreads();   // buf (ch&1) free; Bls[(ch+1)&1] fully staged
    }

    // D layout: col = lane&15 (center), row-in-tile = quad*4 + e.
    // global lag row = 64wu + 16r + 4quad + e; phantom row 1023 excluded.
    float vmax = -INFINITY;
    #pragma unroll
    for (int r = 0; r < 4; ++r) {
        #pragma unroll
        for (int e = 0; e < 4; ++e) {
            bool phantom = (wu == 15) & (r == 3) & (quad == 3) & (e == 3);
            vmax = fmaxf(vmax, phantom ? -INFINITY : acc[r][e]);
        }
    }
    vmax = fmaxf(vmax, __shfl_xor(vmax, 16));
    vmax = fmaxf(vmax, __shfl_xor(vmax, 32));
    if (quad == 0) wred[wu][m] = vmax;
    __syncthreads();

    if (tid < 16) {
        float mm = wred[0][tid];
        #pragma unroll
        for (int i = 1; i < 16; ++i) mm = fmaxf(mm, wred[i][tid]);
        float denom = s_norm * (float)tid;
        float d = (denom < 1e-9f) ? 0.f : mm / denom;
        dd[tid] = d;
        out[NB + b * NK + tid] = d;
    }
    __syncthreads();
    if (tid == 0) {
        float best = dd[0]; int lab = 0;
        #pragma unroll
        for (int k = 1; k < NK; ++k) if (dd[k] > best) { best = dd[k]; lab = k; }
        out[b] = (float)lab;
    }
}

extern "C" void kernel_launch(void* const* d_in, const int* in_sizes, int n_in,
                              void* d_out, int out_size, void* d_ws, size_t ws_size,
                              hipStream_t stream) {
    const float* x = (const float*)d_in[0];
    const float* c = (const float*)d_in[1];
    float* out = (float*)d_out;
    __bf16* bpk = (__bf16*)d_ws;    // 128 kc * 1 KB = 128 KB

    pack_kernel<<<128, 64, 0, stream>>>(c, bpk);
    dists_mfma<<<NB, 1024, 0, stream>>>(x, bpk, out);
}